// Round 5
// baseline (171.313 us; speedup 1.0000x reference)
//
#include <hip/hip_runtime.h>
#include <hip/hip_fp16.h>

// GCN-style symmetric-normalized CSR aggregation.
// out[d][f] = sum_e feat[col_idx[e]][f] * rsqrt(deg[d]*deg[col_idx[e]])
//
// Round-11 theory: LOAD-IMBALANCE TAIL. Five issue-side schedules all land
// at ~45us while VALUBusy swings 33->47% and OccupancyPercent FALLS as waves
// get more persistent (48->31%): waves retire unevenly and the back half of
// the kernel runs nearly empty. Per-wave work was Sum of ~7 pairs'
// max(deg0,deg1), deg~Exp(16) -> slowest waves ~2-2.5x mean.
// Fix: partition EDGES, not rows. Wave w owns edges [w*epw,(w+1)*epw),
// epw ~196 -- identical work per wave by construction. Binary-search
// row_ptr for the row range; rows fully inside -> plain store; rows split
// across waves (~8K) -> atomicAdd of scaled partials onto memset-0 out.

typedef float    v4f __attribute__((ext_vector_type(4)));
typedef unsigned v4u __attribute__((ext_vector_type(4)));

// ---------------- pass 1: fold rsqrt(deg[src]) -> fp16 table (+ zero row) ---
__global__ __launch_bounds__(256) void conv_fold(
    const float4* __restrict__ in, const float* __restrict__ deg,
    uint2* __restrict__ out, int n4)
{
    const int i = blockIdx.x * blockDim.x + threadIdx.x;
    if (i >= n4 + 16) return;
    if (i >= n4) { out[i] = make_uint2(0u, 0u); return; }  // zero row @ n_nodes
    const float w = rsqrtf(deg[i >> 4]);   // 16 float4 per 64-float row
    const float4 f = in[i];
    union { __half2 h; unsigned u; } a, b;
    a.h = __floats2half2_rn(f.x * w, f.y * w);
    b.h = __floats2half2_rn(f.z * w, f.w * w);
    out[i] = make_uint2(a.u, b.u);
}

// max r with row_ptr[r] <= e  (empty rows have zero width -> last start wins)
__device__ __forceinline__ int row_of(const int* __restrict__ rp, int n_nodes, int e)
{
    int lo = 0, hi = n_nodes - 1;
    while (lo < hi) {
        const int mid = (lo + hi + 1) >> 1;
        if (rp[mid] <= e) lo = mid; else hi = mid - 1;
    }
    return lo;
}

// ---------------- pass 2: edge-balanced gather ------------------------------
__global__ __launch_bounds__(256, 8) void gcn_edgebal(
    const int* __restrict__ row_ptr,
    const int* __restrict__ col_idx,
    const unsigned* __restrict__ feath,   // fp16, weight-folded, 128B rows
    const float* __restrict__ deg,
    float* __restrict__ out,
    int n_nodes, int n_edges, int epw)
{
    const int lane = threadIdx.x & 63;
    const int slot = lane >> 3;        // edge slot 0..7 within the row
    const int k    = lane & 7;         // 16B chunk within 128B fp16 row
    const int kb   = k << 4;
    const char* hbase = (const char*)feath;
    const int zrow = n_nodes;

    const int wid = (blockIdx.x * blockDim.x + threadIdx.x) >> 6;
    const long long e_lo_l = (long long)wid * epw;
    if (e_lo_l >= n_edges) return;
    const int e_lo = (int)e_lo_l;
    const int e_hi = min(e_lo + epw, n_edges);

    int r = row_of(row_ptr, n_nodes, e_lo);
    const int r_end = row_of(row_ptr, n_nodes, e_hi - 1);
    int rp_r = row_ptr[r];

    for (;;) {
        const int rp_n = row_ptr[r + 1];
        const int s = max(rp_r, e_lo);
        const int t = min(rp_n, e_hi);

        float acc[8] = {0.f, 0.f, 0.f, 0.f, 0.f, 0.f, 0.f, 0.f};

        for (int g = s; g < t; g += 32) {
            // issue up to 4 independent 16B gathers before consuming any
            v4u q[4];
#pragma unroll
            for (int u = 0; u < 4; ++u) {
                const int e = g + u * 8 + slot;
                int sidx = zrow;                 // dead edges -> L1-hot zero row
                if (e < t) sidx = col_idx[e];    // in-bounds by construction
                q[u] = *reinterpret_cast<const v4u*>(
                    hbase + (((unsigned)sidx) << 7) + kb);
            }
            __builtin_amdgcn_sched_barrier(0);
#pragma unroll
            for (int u = 0; u < 4; ++u) {
#pragma unroll
                for (int p = 0; p < 4; ++p) {
                    union { unsigned uu; __half2 h; } c;
                    c.uu = q[u][p];
                    const float2 f = __half22float2(c.h);
                    acc[2 * p]     += f.x;
                    acc[2 * p + 1] += f.y;
                }
            }
        }

        // reduce across the 8 slots (lane bits 3,4,5)
#pragma unroll
        for (int m = 8; m <= 32; m <<= 1) {
#pragma unroll
            for (int i = 0; i < 8; ++i) acc[i] += __shfl_xor(acc[i], m);
        }

        if (slot == 0) {                       // 8 lanes, k = 0..7
            const float dinv = rsqrtf(deg[r]); // deg clamped >= 1 by setup
            const bool owned = (rp_r >= e_lo) & (rp_n <= e_hi);
            char* po = (char*)out + (((unsigned)r) << 8) + (k << 5);
            if (owned) {
                v4f lo = {acc[0] * dinv, acc[1] * dinv, acc[2] * dinv, acc[3] * dinv};
                v4f hi = {acc[4] * dinv, acc[5] * dinv, acc[6] * dinv, acc[7] * dinv};
                __builtin_nontemporal_store(lo, reinterpret_cast<v4f*>(po));
                __builtin_nontemporal_store(hi, reinterpret_cast<v4f*>(po + 16));
            } else {
                float* pf = reinterpret_cast<float*>(po);
#pragma unroll
                for (int i = 0; i < 8; ++i) atomicAdd(pf + i, acc[i] * dinv);
            }
        }

        if (r == r_end) break;
        ++r; rp_r = rp_n;
    }
}

// ---------------- fallback: fp32 gather (round-3 kernel) --------------------
__global__ __launch_bounds__(256) void gcn_csr_agg_f(
    const int* __restrict__ row_ptr,
    const int* __restrict__ col_idx,
    const float* __restrict__ feat,
    const float* __restrict__ deg,
    float* __restrict__ out,
    int n_nodes)
{
    const int gtid = blockIdx.x * blockDim.x + threadIdx.x;
    const int row  = gtid >> 6;
    if (row >= n_nodes) return;
    const int lane = threadIdx.x & 63;
    const int sub  = lane >> 4;
    const int fbyte = (lane & 15) << 4;

    const int start = row_ptr[row];
    const int end   = row_ptr[row + 1];
    const int last  = end - 1;
    const float dinv = rsqrtf(deg[row]);
    const char* fbase = (const char*)feat;

    v4f acc = {0.f, 0.f, 0.f, 0.f};

    for (int eb = start; eb < end; eb += 16) {
        int e[4]; int s[4]; float d[4]; v4f f[4];
#pragma unroll
        for (int u = 0; u < 4; ++u) {
            e[u] = eb + sub + 4 * u;
            const int c = min(e[u], last);
            s[u] = col_idx[c];
        }
#pragma unroll
        for (int u = 0; u < 4; ++u) {
            d[u] = deg[s[u]];
            const unsigned off = ((unsigned)s[u] << 8) + fbyte;
            f[u] = *reinterpret_cast<const v4f*>(fbase + off);
        }
#pragma unroll
        for (int u = 0; u < 4; ++u) {
            const float w = (e[u] <= last) ? dinv * rsqrtf(d[u]) : 0.f;
            acc += w * f[u];
        }
    }

    acc.x += __shfl_xor(acc.x, 16); acc.y += __shfl_xor(acc.y, 16);
    acc.z += __shfl_xor(acc.z, 16); acc.w += __shfl_xor(acc.w, 16);
    acc.x += __shfl_xor(acc.x, 32); acc.y += __shfl_xor(acc.y, 32);
    acc.z += __shfl_xor(acc.z, 32); acc.w += __shfl_xor(acc.w, 32);

    if (sub == 0) {
        v4f* po = reinterpret_cast<v4f*>((char*)out + ((unsigned)row << 8) + fbyte);
        __builtin_nontemporal_store(acc, po);
    }
}

extern "C" void kernel_launch(void* const* d_in, const int* in_sizes, int n_in,
                              void* d_out, int out_size, void* d_ws, size_t ws_size,
                              hipStream_t stream) {
    const int*   row_ptr = (const int*)d_in[0];
    const int*   col_idx = (const int*)d_in[1];
    const float* feat    = (const float*)d_in[2];
    const float* deg     = (const float*)d_in[3];
    float*       out     = (float*)d_out;

    const int n_nodes = in_sizes[0] - 1;
    const int n_edges = in_sizes[1];
    const int n_feat_elems = in_sizes[2];            // n_nodes * 64
    const size_t h_bytes = (size_t)(n_feat_elems + 64) * 2; // fp16 + zero row

    const int block = 256;

    if (ws_size >= h_bytes && n_edges > 0) {
        const int n4 = n_feat_elems >> 2;
        const int cgrid = (n4 + 16 + block - 1) / block;
        conv_fold<<<cgrid, block, 0, stream>>>(
            (const float4*)feat, deg, (uint2*)d_ws, n4);

        // zero out for atomic partials on split rows (graph-capture safe)
        hipMemsetAsync(d_out, 0, (size_t)out_size, stream);

        const int target_waves = 8192;                   // 8 waves/CU x 256 CU x 4
        const int epw = (n_edges + target_waves - 1) / target_waves;
        const int waves = (n_edges + epw - 1) / epw;
        const int grid = (int)(((long long)waves * 64 + block - 1) / block);
        gcn_edgebal<<<grid, block, 0, stream>>>(
            row_ptr, col_idx, (const unsigned*)d_ws, deg, out,
            n_nodes, n_edges, epw);
    } else {
        const long long threads = (long long)n_nodes * 64;
        const int grid  = (int)((threads + block - 1) / block);
        gcn_csr_agg_f<<<grid, block, 0, stream>>>(
            row_ptr, col_idx, feat, deg, out, n_nodes);
    }
}

// Round 6
// 135.694 us; speedup vs baseline: 1.2625x; 1.2625x over previous
//
#include <hip/hip_runtime.h>
#include <hip/hip_fp16.h>

// GCN-style symmetric-normalized CSR aggregation.
// out[d][f] = sum_e feat[col_idx[e]][f] * rsqrt(deg[d]*deg[col_idx[e]])
//
// Round-12 theory: the invariant across r7-r11 is the line-service rate:
// 3.2M random 64B lines in ~45us = 0.114 lines/cyc/CU, ~39 in flight/CU
// (Little's law). Scheduling/occupancy/balance all exonerated. FETCH_SIZE
// (= L2-miss traffic) says L2 hit = 61% on a 12.8MB table vs 4MB/XCD.
// Lever: LATENCY. Split the table into two 6.4MB half-feature tables
// (64B rows) and gather in two temporally-separated passes -> per-pass
// working set ~fits L2, hit rate ~80%, avg latency ~340->~230cyc, and at
// fixed in-flight concurrency, throughput rises proportionally.
// Same fp16 math -> absmax unchanged.

typedef float    v4f __attribute__((ext_vector_type(4)));
typedef unsigned v4u __attribute__((ext_vector_type(4)));

// ---- pass 1: fold rsqrt(deg[src]) -> two fp16 half-tables (+ zero rows) ----
// T0[r] = fp16(feat[r][0:32]*w), T1[r] = fp16(feat[r][32:64]*w); 64B rows.
__global__ __launch_bounds__(256) void conv_fold_split(
    const float4* __restrict__ in, const float* __restrict__ deg,
    uint2* __restrict__ t0, uint2* __restrict__ t1, int n4)
{
    const int i = blockIdx.x * blockDim.x + threadIdx.x;
    if (i >= n4 + 16) return;
    if (i >= n4) {                       // zero row @ n_nodes in each table
        const int extra = i - n4;        // 0..15
        uint2* t = (extra & 8) ? t1 : t0;
        t[(size_t)(n4 >> 4) * 8 + (extra & 7)] = make_uint2(0u, 0u);
        return;
    }
    const int r = i >> 4;                // 16 float4 per 64-float row
    const int j = i & 15;
    const float w = rsqrtf(deg[r]);
    const float4 f = in[i];
    union { __half2 h; unsigned u; } a, b;
    a.h = __floats2half2_rn(f.x * w, f.y * w);
    b.h = __floats2half2_rn(f.z * w, f.w * w);
    uint2* t = (j & 8) ? t1 : t0;
    t[(size_t)r * 8 + (j & 7)] = make_uint2(a.u, b.u);
}

// ---- pass 2/3: half-feature gather, 2 rows/wave, 1 line per edge ----------
__global__ __launch_bounds__(256, 4) void gcn_half(
    const int* __restrict__ row_ptr,
    const int* __restrict__ col_idx,
    const unsigned* __restrict__ tb,     // fp16 half-table, 64B rows
    const float* __restrict__ deg,
    float* __restrict__ out,
    int n_nodes, int n_edges, int obase) // obase: 0 or 128 byte offset in row
{
    const int lane = threadIdx.x & 63;
    const int half = lane >> 5;        // which of the 2 dest rows
    const int l32  = lane & 31;
    const int slot = l32 >> 2;         // edge slot 0..7 within the half
    const int k    = lane & 3;         // 16B chunk within 64B half-row
    const int kb   = k << 4;
    const char* hbase = (const char*)tb;
    const int Em1  = n_edges - 1;
    const int zrow = n_nodes;

    const int wid = (blockIdx.x * blockDim.x + threadIdx.x) >> 6;
    const int nw  = (gridDim.x * blockDim.x) >> 6;
    const int npairs = (n_nodes + 1) >> 1;
    if (wid >= npairs) return;

    int pair  = wid;
    int row   = min(pair * 2 + half, n_nodes - 1);
    int start = row_ptr[row];
    int end   = row_ptr[row + 1];
    float dcur = deg[row];

    for (;;) {
        // prefetch next pair's bounds + deg (hidden under the gather)
        const int npair  = pair + nw;
        const int nrow   = min(min(npair, npairs - 1) * 2 + half, n_nodes - 1);
        const int nstart = row_ptr[nrow];
        const int nend   = row_ptr[nrow + 1];
        const float ndeg = deg[nrow];

        const int deg_r = end - start;
        const int degM  = max(deg_r, __shfl_xor(deg_r, 32));

        float acc[8] = {0.f, 0.f, 0.f, 0.f, 0.f, 0.f, 0.f, 0.f};

        for (int base = 0; base < degM; base += 32) {
            // per-lane col_idx (4-lane broadcast, L1-hot stream)
            int s[4];
#pragma unroll
            for (int u = 0; u < 4; ++u) {
                const int e = start + base + slot + 8 * u;
                const int c = col_idx[min(e, Em1)];
                s[u] = (e < end) ? c : zrow;   // tail -> zero row
            }
            // issue all 4 gathers (8 lines each per half) before consuming
            v4u q[4];
#pragma unroll
            for (int u = 0; u < 4; ++u)
                q[u] = *reinterpret_cast<const v4u*>(
                    hbase + (((unsigned)s[u]) << 6) + kb);
            __builtin_amdgcn_sched_barrier(0);
#pragma unroll
            for (int u = 0; u < 4; ++u) {
#pragma unroll
                for (int p = 0; p < 4; ++p) {
                    union { unsigned uu; __half2 h; } c;
                    c.uu = q[u][p];
                    const float2 f = __half22float2(c.h);
                    acc[2 * p]     += f.x;
                    acc[2 * p + 1] += f.y;
                }
            }
        }

        // reduce across the 8 slots of each half (lane bits 2,3,4)
#pragma unroll
        for (int m = 4; m <= 16; m <<= 1) {
#pragma unroll
            for (int i = 0; i < 8; ++i) acc[i] += __shfl_xor(acc[i], m);
        }

        if (slot == 0) {                   // 4 lanes per half, k = 0..3
            const float dinv = rsqrtf(dcur);
            v4f lo = {acc[0] * dinv, acc[1] * dinv, acc[2] * dinv, acc[3] * dinv};
            v4f hi = {acc[4] * dinv, acc[5] * dinv, acc[6] * dinv, acc[7] * dinv};
            char* po = (char*)out + (((unsigned)row) << 8) + obase + (k << 5);
            __builtin_nontemporal_store(lo, reinterpret_cast<v4f*>(po));
            __builtin_nontemporal_store(hi, reinterpret_cast<v4f*>(po + 16));
        }

        if (npair >= npairs) break;
        pair = npair; row = nrow; start = nstart; end = nend; dcur = ndeg;
    }
}

// ---------------- fallback: fp32 gather (round-3 kernel) --------------------
__global__ __launch_bounds__(256) void gcn_csr_agg_f(
    const int* __restrict__ row_ptr,
    const int* __restrict__ col_idx,
    const float* __restrict__ feat,
    const float* __restrict__ deg,
    float* __restrict__ out,
    int n_nodes)
{
    const int gtid = blockIdx.x * blockDim.x + threadIdx.x;
    const int row  = gtid >> 6;
    if (row >= n_nodes) return;
    const int lane = threadIdx.x & 63;
    const int sub  = lane >> 4;
    const int fbyte = (lane & 15) << 4;

    const int start = row_ptr[row];
    const int end   = row_ptr[row + 1];
    const int last  = end - 1;
    const float dinv = rsqrtf(deg[row]);
    const char* fbase = (const char*)feat;

    v4f acc = {0.f, 0.f, 0.f, 0.f};

    for (int eb = start; eb < end; eb += 16) {
        int e[4]; int s[4]; float d[4]; v4f f[4];
#pragma unroll
        for (int u = 0; u < 4; ++u) {
            e[u] = eb + sub + 4 * u;
            const int c = min(e[u], last);
            s[u] = col_idx[c];
        }
#pragma unroll
        for (int u = 0; u < 4; ++u) {
            d[u] = deg[s[u]];
            const unsigned off = ((unsigned)s[u] << 8) + fbyte;
            f[u] = *reinterpret_cast<const v4f*>(fbase + off);
        }
#pragma unroll
        for (int u = 0; u < 4; ++u) {
            const float w = (e[u] <= last) ? dinv * rsqrtf(d[u]) : 0.f;
            acc += w * f[u];
        }
    }

    acc.x += __shfl_xor(acc.x, 16); acc.y += __shfl_xor(acc.y, 16);
    acc.z += __shfl_xor(acc.z, 16); acc.w += __shfl_xor(acc.w, 16);
    acc.x += __shfl_xor(acc.x, 32); acc.y += __shfl_xor(acc.y, 32);
    acc.z += __shfl_xor(acc.z, 32); acc.w += __shfl_xor(acc.w, 32);

    if (sub == 0) {
        v4f* po = reinterpret_cast<v4f*>((char*)out + ((unsigned)row << 8) + fbyte);
        __builtin_nontemporal_store(acc, po);
    }
}

extern "C" void kernel_launch(void* const* d_in, const int* in_sizes, int n_in,
                              void* d_out, int out_size, void* d_ws, size_t ws_size,
                              hipStream_t stream) {
    const int*   row_ptr = (const int*)d_in[0];
    const int*   col_idx = (const int*)d_in[1];
    const float* feat    = (const float*)d_in[2];
    const float* deg     = (const float*)d_in[3];
    float*       out     = (float*)d_out;

    const int n_nodes = in_sizes[0] - 1;
    const int n_edges = in_sizes[1];
    const int n_feat_elems = in_sizes[2];            // n_nodes * 64
    const size_t t_bytes = ((size_t)n_nodes + 1) * 64;  // one half-table
    const int block = 256;

    if (ws_size >= 2 * t_bytes && n_edges > 0) {
        uint2* t0 = (uint2*)d_ws;
        uint2* t1 = (uint2*)((char*)d_ws + t_bytes);

        const int n4 = n_feat_elems >> 2;
        const int cgrid = (n4 + 16 + block - 1) / block;
        conv_fold_split<<<cgrid, block, 0, stream>>>(
            (const float4*)feat, deg, t0, t1, n4);

        const int npairs = (n_nodes + 1) >> 1;
        const int max_blocks = 2048;                  // persistent grid
        long long need_blocks = ((long long)npairs * 64 + block - 1) / block;
        const int grid = (int)(need_blocks < max_blocks ? need_blocks : max_blocks);

        gcn_half<<<grid, block, 0, stream>>>(
            row_ptr, col_idx, (const unsigned*)t0, deg, out, n_nodes, n_edges, 0);
        gcn_half<<<grid, block, 0, stream>>>(
            row_ptr, col_idx, (const unsigned*)t1, deg, out, n_nodes, n_edges, 128);
    } else {
        const long long threads = (long long)n_nodes * 64;
        const int grid  = (int)((threads + block - 1) / block);
        gcn_csr_agg_f<<<grid, block, 0, stream>>>(
            row_ptr, col_idx, feat, deg, out, n_nodes);
    }
}